// Round 5
// baseline (1214.095 us; speedup 1.0000x reference)
//
#include <hip/hip_runtime.h>
#include <hip/hip_fp16.h>

static constexpr int B  = 4;
static constexpr int H0 = 256, W0 = 448, HW0 = H0 * W0;   // full
static constexpr int H1 = 128, W1 = 224, HW1 = H1 * W1;   // half
static constexpr int H2 = 64,  W2 = 112, HW2 = H2 * W2;   // quarter
static constexpr float PI_F = 3.14159265358979323846f;

typedef _Float16 half8_t __attribute__((ext_vector_type(8)));
typedef _Float16 half4_t __attribute__((ext_vector_type(4)));
typedef float floatx4 __attribute__((ext_vector_type(4)));

static constexpr int NCELL_MAX = (W0 + 1) * (H0 + 1);     // 115393

// record strides in dwords
static constexpr int RS_F = 20;   // full: u0=(im0,im1) u1=(im2,sig) u2..17=feat pairs u18=fx u19=fy
static constexpr int RS_H = 36;   // 64 ch pairs + fx,fy + pad
static constexpr int RS_Q = 52;   // 96 ch pairs + fx,fy + pad

// ---------------- workspace layout (floats) ----------------
static constexpr size_t OFF_MEAN   = 0;                          // 256 (4 used)
static constexpr size_t OFF_IMGC   = 256;                        // 8*3*HW0 (planar f32)
static constexpr size_t OFF_BUFA   = OFF_IMGC + (size_t)8 * 3 * HW0;   // ping (NHWC f16 / records+buckets)
static constexpr size_t OFF_BUFB   = OFF_BUFA + (size_t)4 * 32 * HW0;  // pong (NHWC f16)
static constexpr size_t OFF_FLOW0  = OFF_BUFB + (size_t)4 * 32 * HW0;  // B*2*HW0
static constexpr size_t OFF_FLOW1  = OFF_FLOW0 + (size_t)B * 2 * HW0;
static constexpr size_t OFF_FL0H   = OFF_FLOW1 + (size_t)B * 2 * HW0;  // B*2*HW1
static constexpr size_t OFF_FL1H   = OFF_FL0H + (size_t)B * 2 * HW1;
static constexpr size_t OFF_FL0Q   = OFF_FL1H + (size_t)B * 2 * HW1;   // B*2*HW2
static constexpr size_t OFF_FL1Q   = OFF_FL0Q + (size_t)B * 2 * HW2;
// transformed weights wT[q][co][ci] f16 (dword counts = 9*CO*CI/2)
static constexpr size_t OFF_WT2 = OFF_FL1Q + (size_t)B * 2 * HW2;  // 9*32*32/2 = 4608
static constexpr size_t OFF_WT3 = OFF_WT2 + 4608;                  // 9*64*32/2 = 9216
static constexpr size_t OFF_WT4 = OFF_WT3 + 9216;                  // 9*64*64/2 = 18432
static constexpr size_t OFF_WT5 = OFF_WT4 + 18432;                 // 9*96*64/2 = 27648
static constexpr size_t OFF_WT6 = OFF_WT5 + 27648;                 // 9*96*96/2 = 41472
// keep the old (larger) footprint requirement for safety margin
static constexpr size_t WS_FLOATS = OFF_WT6 + 41472 + (size_t)2 * B * (HW0 + HW1 + HW2);

// inside BUFA (dword offsets): records, then exact-bucket arrays. BUFA = 14,680,064 dwords.
static constexpr size_t REC_DWORDS = (size_t)B * HW0 * RS_F;         // 9,175,040
static constexpr size_t BKT_CNT    = REC_DWORDS;                     // B*NCELL_MAX
static constexpr size_t BKT_TOTAL  = BKT_CNT + (size_t)B * NCELL_MAX;  // 16
static constexpr size_t BKT_START  = BKT_TOTAL + 16;                 // B*NCELL_MAX
static constexpr size_t BKT_CURS   = BKT_START + (size_t)B * NCELL_MAX;
static constexpr size_t BKT_LIST   = BKT_CURS + (size_t)B * NCELL_MAX; // B*HW0
static constexpr size_t BKT_END    = BKT_LIST + (size_t)B * HW0;
static_assert(BKT_END <= (size_t)4 * 32 * HW0, "records+buckets must fit in BUFA");
static constexpr size_t BKT_ZERO_BYTES = ((size_t)B * NCELL_MAX + 16) * 4;  // CNT + TOTAL

// ---------------- output layout (floats) ----------------
static constexpr size_t O_IMG = 0;                                // B*6*HW0
static constexpr size_t O_F1  = O_IMG + (size_t)B * 6 * HW0;      // B*64*HW0
static constexpr size_t O_F2  = O_F1  + (size_t)B * 64 * HW0;     // B*128*HW1
static constexpr size_t O_F3  = O_F2  + (size_t)B * 128 * HW1;    // B*192*HW2
static constexpr size_t O_SIG = O_F3  + (size_t)B * 192 * HW2;    // B*2*HW0

// f16 pair <-> float helpers
__device__ inline void h2f(unsigned u, float& lo, float& hi) {
  __half2 h = *reinterpret_cast<__half2*>(&u);
  float2 f = __half22float2(h);
  lo = f.x; hi = f.y;
}
__device__ inline unsigned f2h(float lo, float hi) {
  __half2 h = __floats2half2_rn(lo, hi);
  return *reinterpret_cast<unsigned*>(&h);
}

// ---------------- mean over (img0,img1) per batch ----------------
__global__ __launch_bounds__(256) void k_mean(const float* __restrict__ img0,
                                              const float* __restrict__ img1,
                                              float* __restrict__ msum, int perImg) {
  int b = blockIdx.y;
  float s = 0.f;
  int tot = 2 * perImg;
  for (int i = blockIdx.x * blockDim.x + threadIdx.x; i < tot; i += gridDim.x * blockDim.x) {
    s += (i < perImg) ? img0[(size_t)b * perImg + i] : img1[(size_t)b * perImg + (i - perImg)];
  }
#pragma unroll
  for (int o = 32; o > 0; o >>= 1) s += __shfl_down(s, o);
  __shared__ float red[4];
  int lane = threadIdx.x & 63, wid = threadIdx.x >> 6;
  if (lane == 0) red[wid] = s;
  __syncthreads();
  if (threadIdx.x == 0) atomicAdd(&msum[b], red[0] + red[1] + red[2] + red[3]);
}

__global__ __launch_bounds__(256) void k_submean(const float* __restrict__ img0,
                                                 const float* __restrict__ img1,
                                                 const float* __restrict__ msum,
                                                 float* __restrict__ imgc, float invCnt) {
  const int perImg = 3 * HW0;
  int i = blockIdx.x * 256 + threadIdx.x;
  if (i >= 8 * perImg) return;
  int n = i / perImg;
  int r = i - n * perImg;
  int b = n & 3;
  float m = msum[b] * invCnt;
  float v = (n < 4) ? img0[(size_t)b * perImg + r] : img1[(size_t)b * perImg + r];
  imgc[i] = v - m;
}

// ---------------- cal_inter_flow (t = 0.5 both dirs) ----------------
__global__ __launch_bounds__(256) void k_interflow(const float* __restrict__ flo,
                                                   const float* __restrict__ sigma,
                                                   float* __restrict__ out, float t) {
  int i = blockIdx.x * 256 + threadIdx.x;
  if (i >= B * HW0) return;
  int b = i / HW0, px = i - b * HW0;
  float fx = flo[((size_t)(b * 2 + 0)) * HW0 + px];
  float fy = flo[((size_t)(b * 2 + 1)) * HW0 + px];
  float sg = sigma[(size_t)b * HW0 + px];
  float ftx, fty;
  if (fabsf(sg) < 0.01f) {
    ftx = t * fx;
    fty = t * fy;
  } else {
    float alpha = atan2f(fy, fx);
    float beta  = asinf(sg);
    float d = sqrtf(fx * fx + fy * fy);
    float R = d / (2.f * sg);
    float th0 = alpha + 0.5f * PI_F + beta;
    float th1 = alpha + 0.5f * PI_F - beta;
    float tht = th0 + (th1 - th0) * t;
    ftx = R * (cosf(tht) - cosf(th0));
    fty = R * (sinf(tht) - sinf(th0));
  }
  out[((size_t)(b * 2 + 0)) * HW0 + px] = ftx;
  out[((size_t)(b * 2 + 1)) * HW0 + px] = fty;
}

// ---------------- antialiased bilinear downsample by integer F, ×(1/F) ----------------
__global__ __launch_bounds__(256) void k_downflow(const float* __restrict__ in,
                                                  float* __restrict__ out,
                                                  int Hin, int Win, int Hout, int Wout, int F) {
  int total = 2 * B * Hout * Wout;
  int i = blockIdx.x * 256 + threadIdx.x;
  if (i >= total) return;
  int ow = i % Wout;
  int t  = i / Wout;
  int oh = t % Hout;
  int bc = t / Hout;
  float cy = (oh + 0.5f) * F - 0.5f;
  float cx = (ow + 0.5f) * F - 0.5f;
  int ylo = (int)floorf(cy) - F + 1;
  int xlo = (int)floorf(cx) - F + 1;
  const float* ip = in + (size_t)bc * Hin * Win;
  float acc = 0.f, wn = 0.f;
  for (int jy = 0; jy < 2 * F; jy++) {
    int y = ylo + jy;
    if ((unsigned)y >= (unsigned)Hin) continue;
    float wy = 1.f - fabsf((float)y - cy) / (float)F;
    for (int jx = 0; jx < 2 * F; jx++) {
      int x = xlo + jx;
      if ((unsigned)x >= (unsigned)Win) continue;
      float wx = 1.f - fabsf((float)x - cx) / (float)F;
      float ww = wy * wx;
      acc += ww * ip[(size_t)y * Win + x];
      wn += ww;
    }
  }
  out[i] = (acc / wn) * (1.f / (float)F);
}

// ---------------- weight transform: [co][ci][3][3] f32 -> [q][co][ci] f16 ----------------
__global__ __launch_bounds__(256) void k_wtrans(const float* __restrict__ w,
                                                _Float16* __restrict__ o,
                                                int COUT, int CIN) {
  int i = blockIdx.x * 256 + threadIdx.x;
  int tot = COUT * CIN * 9;
  if (i >= tot) return;
  int q = i % 9;
  int rest = i / 9;
  int ci = rest % CIN;
  int co = rest / CIN;
  o[((size_t)q * COUT + co) * CIN + ci] = (_Float16)w[i];
}

// ---------------- conv1: 3->32, VALU, planar f32 in -> NHWC f16 out ----------------
__global__ __launch_bounds__(256) void conv1_nhwc(
    const float* __restrict__ in, const float* __restrict__ wgt,
    const float* __restrict__ bias, const float* __restrict__ alpha,
    _Float16* __restrict__ outp) {
  __shared__ float wsm[8 * 3 * 9];
  int co0 = blockIdx.y * 8;
  int n = blockIdx.z;
  for (int i = threadIdx.x; i < 8 * 3 * 9; i += 256) wsm[i] = wgt[co0 * 27 + i];
  __syncthreads();
  int tx = blockIdx.x % 7, ty = blockIdx.x / 7;
  int ow = tx * 64 + (threadIdx.x & 63);
  int oh = ty * 4 + (threadIdx.x >> 6);
  float acc[8];
#pragma unroll
  for (int k = 0; k < 8; k++) acc[k] = bias[co0 + k];
  const float* ip = in + (size_t)n * 3 * HW0;
  for (int ci = 0; ci < 3; ci++) {
    const float* iq = ip + (size_t)ci * HW0;
    float xv[9];
#pragma unroll
    for (int ky = 0; ky < 3; ky++) {
      int y = oh - 1 + ky;
      bool yv = (unsigned)y < (unsigned)H0;
      const float* row = iq + (size_t)y * W0;
#pragma unroll
      for (int kx = 0; kx < 3; kx++) {
        int x = ow - 1 + kx;
        xv[ky * 3 + kx] = (yv && (unsigned)x < (unsigned)W0) ? row[x] : 0.f;
      }
    }
#pragma unroll
    for (int k = 0; k < 8; k++) {
      const float* wp = &wsm[(k * 3 + ci) * 9];
#pragma unroll
      for (int q = 0; q < 9; q++) acc[k] += xv[q] * wp[q];
    }
  }
  float a = alpha[0];
  half8_t h;
#pragma unroll
  for (int k = 0; k < 8; k++) {
    float v = acc[k];
    v = v > 0.f ? v : a * v;
    h[k] = (_Float16)v;
  }
  *(half8_t*)(outp + ((size_t)(n * H0 + oh) * W0 + ow) * 32 + co0) = h;
}

// ---------------- MFMA conv: NHWC f16 in, wT f16, NHWC f16 out ----------------
template <int CIN, int COUT, int STRIDE>
__global__ __launch_bounds__(256) void conv_mfma(
    const _Float16* __restrict__ in, const _Float16* __restrict__ wT,
    const float* __restrict__ bias, const float* __restrict__ alpha,
    _Float16* __restrict__ outp, int Hin, int Win, int Hout, int Wout) {
  int gx = gridDim.x, gy = gridDim.y, gz = gridDim.z;
  int T = gx * gy * gz;
  int lb = ((int)blockIdx.z * gy + blockIdx.y) * gx + blockIdx.x;
  lb = (lb & 7) * (T >> 3) + (lb >> 3);      // co fastest, n, tile slowest
  int cob  = lb % gy;
  int n    = (lb / gy) % gz;
  int tile = lb / (gy * gz);
  int lane = threadIdx.x & 63, wave = threadIdx.x >> 6;
  int l15 = lane & 15, lhi = lane >> 4;
  int wco = wave & 1, wrow = wave >> 1;
  int tiles_x = Wout >> 4;
  int tx = tile % tiles_x, ty = tile / tiles_x;
  int ow0 = tx << 4;
  int oh0 = (ty << 3) + (wrow << 2);
  int co0 = cob * 32 + wco * 16;
  floatx4 acc[4] = {};
  const _Float16* ip = in + (size_t)n * Hin * Win * CIN;
  int x_base = (ow0 + l15) * STRIDE;
  const _Float16* wrow_p = wT + (size_t)(co0 + l15) * CIN;
  for (int q = 0; q < 9; q++) {
    int dy = q / 3 - 1, dx = q % 3 - 1;
    int x = x_base + dx;
    bool xv = (unsigned)x < (unsigned)Win;
    int xc = x < 0 ? 0 : (x >= Win ? Win - 1 : x);
    const _Float16* wqq = wrow_p + (size_t)q * COUT * CIN;
#pragma unroll
    for (int kc = 0; kc < CIN / 32; kc++) {
      int ci = kc * 32 + lhi * 8;
      half8_t a = *(const half8_t*)(wqq + ci);
#pragma unroll
      for (int t = 0; t < 4; t++) {
        int y = (oh0 + t) * STRIDE + dy;
        if ((unsigned)y >= (unsigned)Hin) continue;   // wave-uniform
        half8_t bf = *(const half8_t*)(ip + ((size_t)y * Win + xc) * CIN + ci);
        half8_t z = {};
        bf = xv ? bf : z;
        acc[t] = __builtin_amdgcn_mfma_f32_16x16x32_f16(a, bf, acc[t], 0, 0, 0);
      }
    }
  }
  float aP = alpha[0];
  float bia[4];
#pragma unroll
  for (int r = 0; r < 4; r++) bia[r] = bias[co0 + lhi * 4 + r];
#pragma unroll
  for (int t = 0; t < 4; t++) {
    half4_t h;
#pragma unroll
    for (int r = 0; r < 4; r++) {
      float v = acc[t][r] + bia[r];
      v = v > 0.f ? v : aP * v;
      h[r] = (_Float16)v;
    }
    *(half4_t*)(outp + (((size_t)n * Hout + oh0 + t) * Wout + ow0 + l15) * COUT +
                co0 + lhi * 4) = h;
  }
}

// ---------------- pack warp records ----------------
__global__ __launch_bounds__(256) void k_pack_full(
    const float* __restrict__ imgc, const _Float16* __restrict__ featN,
    const float* __restrict__ sig, const float* __restrict__ flow,
    float* __restrict__ recs, int dir) {
  int px = blockIdx.x * 256 + threadIdx.x;
  int b = blockIdx.y;
  if (px >= HW0) return;
  const float* imp = imgc + ((size_t)((dir * 4 + b) * 3)) * HW0;
  float im0 = imp[px], im1 = imp[(size_t)HW0 + px], im2 = imp[(size_t)2 * HW0 + px];
  float sg = sig[(size_t)b * HW0 + px];
  union { floatx4 f4[RS_F / 4]; unsigned u[RS_F]; } r;
  r.u[0] = f2h(im0, im1);
  r.u[1] = f2h(im2, sg);
  const floatx4* fp = (const floatx4*)(featN + (size_t)(b * HW0 + px) * 32);
  union { floatx4 f; unsigned u[4]; } t;
#pragma unroll
  for (int j = 0; j < 4; j++) {
    t.f = fp[j];
    r.u[2 + 4 * j + 0] = t.u[0]; r.u[2 + 4 * j + 1] = t.u[1];
    r.u[2 + 4 * j + 2] = t.u[2]; r.u[2 + 4 * j + 3] = t.u[3];
  }
  r.u[18] = __float_as_uint(flow[((size_t)(b * 2 + 0)) * HW0 + px]);
  r.u[19] = __float_as_uint(flow[((size_t)(b * 2 + 1)) * HW0 + px]);
  floatx4* o = (floatx4*)(recs + (size_t)(b * HW0 + px) * RS_F);
#pragma unroll
  for (int j = 0; j < RS_F / 4; j++) o[j] = r.f4[j];
}

template <int C, int HWd, int RS>
__global__ __launch_bounds__(256) void k_pack_feat(
    const _Float16* __restrict__ featN, const float* __restrict__ flow,
    float* __restrict__ recs) {
  int px = blockIdx.x * 256 + threadIdx.x;
  int b = blockIdx.y;
  if (px >= HWd) return;
  union { floatx4 f4[RS / 4]; unsigned u[RS]; } r;
  const floatx4* fp = (const floatx4*)(featN + (size_t)(b * HWd + px) * C);
#pragma unroll
  for (int j = 0; j < C / 8; j++) r.f4[j] = fp[j];
  r.u[C / 2]     = __float_as_uint(flow[((size_t)(b * 2 + 0)) * HWd + px]);
  r.u[C / 2 + 1] = __float_as_uint(flow[((size_t)(b * 2 + 1)) * HWd + px]);
#pragma unroll
  for (int j = C / 2 + 2; j < RS; j++) r.u[j] = 0;
  floatx4* o = (floatx4*)(recs + (size_t)(b * HWd + px) * RS);
#pragma unroll
  for (int j = 0; j < RS / 4; j++) o[j] = r.f4[j];
}

// ---------------- exact buckets: count -> alloc -> fill ----------------
template <int Hd, int Wd>
__global__ __launch_bounds__(256) void k_bucket_count(
    const float* __restrict__ flow, unsigned* __restrict__ cnt) {
  constexpr int HWd = Hd * Wd;
  constexpr int NCX = Wd + 1;
  constexpr int NC  = (Wd + 1) * (Hd + 1);
  int px = blockIdx.x * 256 + threadIdx.x;
  int b = blockIdx.y;
  if (px >= HWd) return;
  float fx = flow[((size_t)(b * 2 + 0)) * HWd + px];
  float fy = flow[((size_t)(b * 2 + 1)) * HWd + px];
  int sw = px % Wd, sh = px / Wd;
  float tx = (float)sw + fx, ty = (float)sh + fy;
  int x0 = (int)floorf(tx), y0 = (int)floorf(ty);
  if (x0 < -1 || x0 > Wd - 1 || y0 < -1 || y0 > Hd - 1) return;
  atomicAdd(&cnt[b * NC + (y0 + 1) * NCX + (x0 + 1)], 1u);
}

__global__ __launch_bounds__(256) void k_bucket_alloc(
    const unsigned* __restrict__ cnt, unsigned* __restrict__ start,
    unsigned* __restrict__ curs, unsigned* __restrict__ total, int tot) {
  int i = blockIdx.x * 256 + threadIdx.x;
  unsigned c = (i < tot) ? cnt[i] : 0u;
  unsigned pre = c;
  int lane = threadIdx.x & 63;
#pragma unroll
  for (int o = 1; o < 64; o <<= 1) {
    unsigned v = __shfl_up(pre, o);
    if (lane >= o) pre += v;
  }
  unsigned wsum = __shfl(pre, 63);
  unsigned base = 0;
  if (lane == 0) base = atomicAdd(total, wsum);
  base = __shfl(base, 0);
  unsigned st = base + pre - c;     // exclusive prefix within wave + wave base
  if (i < tot) { start[i] = st; curs[i] = st; }
}

template <int Hd, int Wd>
__global__ __launch_bounds__(256) void k_bucket_fill(
    const float* __restrict__ flow, unsigned* __restrict__ curs,
    unsigned* __restrict__ list) {
  constexpr int HWd = Hd * Wd;
  constexpr int NCX = Wd + 1;
  constexpr int NC  = (Wd + 1) * (Hd + 1);
  int px = blockIdx.x * 256 + threadIdx.x;
  int b = blockIdx.y;
  if (px >= HWd) return;
  float fx = flow[((size_t)(b * 2 + 0)) * HWd + px];
  float fy = flow[((size_t)(b * 2 + 1)) * HWd + px];
  int sw = px % Wd, sh = px / Wd;
  float tx = (float)sw + fx, ty = (float)sh + fy;
  int x0 = (int)floorf(tx), y0 = (int)floorf(ty);
  if (x0 < -1 || x0 > Wd - 1 || y0 < -1 || y0 > Hd - 1) return;
  unsigned slot = atomicAdd(&curs[b * NC + (y0 + 1) * NCX + (x0 + 1)], 1u);
  list[slot] = (unsigned)px;
}

// ---------------- full-res gather (normalization fused) ----------------
__global__ __launch_bounds__(256) void k_warp_gather_full(
    const float* __restrict__ recs,
    const unsigned* __restrict__ cnt, const unsigned* __restrict__ start,
    const unsigned* __restrict__ list,
    float* __restrict__ outImg, float* __restrict__ outFeat, float* __restrict__ outSig,
    int dir) {
  constexpr int NCX = W0 + 1;
  constexpr int NC  = (W0 + 1) * (H0 + 1);
  int T = gridDim.x * gridDim.y;
  int lb = (int)blockIdx.y * gridDim.x + blockIdx.x;
  lb = (lb & 7) * (T >> 3) + (lb >> 3);          // XCD chunking
  int b = lb / gridDim.x;
  int q = (lb % gridDim.x) * 256 + (int)threadIdx.x;
  if (q >= HW0) return;
  int qx = q % W0, qy = q / W0;
  float acc[36];
#pragma unroll
  for (int c = 0; c < 36; c++) acc[c] = 0.f;
  float dsum = 0.f;
  for (int ky = 0; ky < 2; ky++) {
    int cy = qy - 1 + ky;
    for (int kx = 0; kx < 2; kx++) {
      int cx = qx - 1 + kx;
      int cidx = b * NC + (cy + 1) * NCX + (cx + 1);
      unsigned cn = cnt[cidx];
      unsigned s0 = start[cidx];
      for (unsigned s = s0; s < s0 + cn; s++) {
        int px = (int)list[s];
        const floatx4* r4 = (const floatx4*)(recs + (size_t)(b * HW0 + px) * RS_F);
        floatx4 a0 = r4[0], a1 = r4[1], a2 = r4[2], a3 = r4[3], a4 = r4[4];
        union { floatx4 f; unsigned u[4]; } t;
        float ch[36]; float fx, fy;
        t.f = a0; h2f(t.u[0], ch[0], ch[1]);   h2f(t.u[1], ch[2], ch[35]);
                  h2f(t.u[2], ch[3], ch[4]);   h2f(t.u[3], ch[5], ch[6]);
        t.f = a1; h2f(t.u[0], ch[7], ch[8]);   h2f(t.u[1], ch[9], ch[10]);
                  h2f(t.u[2], ch[11], ch[12]); h2f(t.u[3], ch[13], ch[14]);
        t.f = a2; h2f(t.u[0], ch[15], ch[16]); h2f(t.u[1], ch[17], ch[18]);
                  h2f(t.u[2], ch[19], ch[20]); h2f(t.u[3], ch[21], ch[22]);
        t.f = a3; h2f(t.u[0], ch[23], ch[24]); h2f(t.u[1], ch[25], ch[26]);
                  h2f(t.u[2], ch[27], ch[28]); h2f(t.u[3], ch[29], ch[30]);
        t.f = a4; h2f(t.u[0], ch[31], ch[32]); h2f(t.u[1], ch[33], ch[34]);
        fx = __uint_as_float(t.u[2]); fy = __uint_as_float(t.u[3]);
        int sw = px % W0, sh = px / W0;
        float tx = (float)sw + fx, ty = (float)sh + fy;
        float dxf = tx - floorf(tx), dyf = ty - floorf(ty);
        float wx = kx ? (1.f - dxf) : dxf;
        float wy = ky ? (1.f - dyf) : dyf;
        float w = wx * wy;
        dsum += w;
#pragma unroll
        for (int c = 0; c < 36; c++) acc[c] += w * ch[c];
      }
    }
  }
  float inv = 1.f / fmaxf(dsum, 1e-7f);
#pragma unroll
  for (int c = 0; c < 3; c++)
    outImg[((size_t)(b * 6 + dir * 3 + c)) * HW0 + q] = acc[c] * inv;
#pragma unroll
  for (int c = 0; c < 32; c++)
    outFeat[((size_t)(b * 64 + dir * 32 + c)) * HW0 + q] = acc[3 + c] * inv;
  outSig[((size_t)(b * 2 + dir)) * HW0 + q] = acc[35] * inv;
}

// ---------------- reduced-res gather: 32-channel chunk per z (normalization fused) ----------------
template <int C, int Hd, int Wd, int RS>
__global__ __launch_bounds__(256) void k_warp_gather_feat(
    const float* __restrict__ recs,
    const unsigned* __restrict__ cnt, const unsigned* __restrict__ start,
    const unsigned* __restrict__ list,
    float* __restrict__ outF, int dir) {
  constexpr int HWd = Hd * Wd;
  constexpr int NCX = Wd + 1;
  constexpr int NC  = (Wd + 1) * (Hd + 1);
  int Z = gridDim.z;
  int T = gridDim.x * gridDim.y * Z;
  int lb = ((int)blockIdx.z * gridDim.y + blockIdx.y) * gridDim.x + blockIdx.x;
  lb = (lb & 7) * (T >> 3) + (lb >> 3);          // XCD chunking, z fastest
  int z = lb % Z;
  int rest = lb / Z;
  int b = rest / gridDim.x;
  int q = (rest % gridDim.x) * 256 + (int)threadIdx.x;
  int c0 = z * 32;
  if (q >= HWd) return;
  int qx = q % Wd, qy = q / Wd;
  float acc[32];
#pragma unroll
  for (int c = 0; c < 32; c++) acc[c] = 0.f;
  float dsum = 0.f;
  for (int ky = 0; ky < 2; ky++) {
    int cy = qy - 1 + ky;
    for (int kx = 0; kx < 2; kx++) {
      int cx = qx - 1 + kx;
      int cidx = b * NC + (cy + 1) * NCX + (cx + 1);
      unsigned cn = cnt[cidx];
      unsigned s0 = start[cidx];
      for (unsigned s = s0; s < s0 + cn; s++) {
        int px = (int)list[s];
        const unsigned* rp = (const unsigned*)(recs + (size_t)(b * HWd + px) * RS);
        const floatx4* r4 = (const floatx4*)rp;
        floatx4 a0 = r4[4 * z + 0], a1 = r4[4 * z + 1], a2 = r4[4 * z + 2], a3 = r4[4 * z + 3];
        float2 hd = *(const float2*)(rp + C / 2);
        union { floatx4 f; unsigned u[4]; } t;
        float ch[32];
        t.f = a0; h2f(t.u[0], ch[0], ch[1]);  h2f(t.u[1], ch[2], ch[3]);
                  h2f(t.u[2], ch[4], ch[5]);  h2f(t.u[3], ch[6], ch[7]);
        t.f = a1; h2f(t.u[0], ch[8], ch[9]);  h2f(t.u[1], ch[10], ch[11]);
                  h2f(t.u[2], ch[12], ch[13]);h2f(t.u[3], ch[14], ch[15]);
        t.f = a2; h2f(t.u[0], ch[16], ch[17]);h2f(t.u[1], ch[18], ch[19]);
                  h2f(t.u[2], ch[20], ch[21]);h2f(t.u[3], ch[22], ch[23]);
        t.f = a3; h2f(t.u[0], ch[24], ch[25]);h2f(t.u[1], ch[26], ch[27]);
                  h2f(t.u[2], ch[28], ch[29]);h2f(t.u[3], ch[30], ch[31]);
        int sw = px % Wd, sh = px / Wd;
        float tx = (float)sw + hd.x, ty = (float)sh + hd.y;
        float dxf = tx - floorf(tx), dyf = ty - floorf(ty);
        float wx = kx ? (1.f - dxf) : dxf;
        float wy = ky ? (1.f - dyf) : dyf;
        float w = wx * wy;
        dsum += w;
#pragma unroll
        for (int c = 0; c < 32; c++) acc[c] += w * ch[c];
      }
    }
  }
  float inv = 1.f / fmaxf(dsum, 1e-7f);
  size_t obase = ((size_t)(b * 2 * C + dir * C + c0)) * HWd + q;
#pragma unroll
  for (int c = 0; c < 32; c++) outF[obase + (size_t)c * HWd] = acc[c] * inv;
}

extern "C" void kernel_launch(void* const* d_in, const int* in_sizes, int n_in,
                              void* d_out, int out_size, void* d_ws, size_t ws_size,
                              hipStream_t stream) {
  (void)in_sizes; (void)n_in; (void)out_size;
  if (ws_size < WS_FLOATS * sizeof(float)) return;  // not enough scratch

  const float* img0    = (const float*)d_in[0];
  const float* img1    = (const float*)d_in[1];
  const float* flow01  = (const float*)d_in[2];
  const float* sigma01 = (const float*)d_in[3];
  const float* flow10  = (const float*)d_in[4];
  const float* sigma10 = (const float*)d_in[5];
  const float* wp[6]; const float* bp[6]; const float* ap[6];
  for (int i = 0; i < 6; i++) {
    wp[i] = (const float*)(d_in[6 + 3 * i]);
    bp[i] = (const float*)(d_in[7 + 3 * i]);
    ap[i] = (const float*)(d_in[8 + 3 * i]);
  }
  float* ws  = (float*)d_ws;
  float* out = (float*)d_out;

  // records + exact buckets alias BUFA (dead between conv-producer and conv-consumer)
  float*    recs  = ws + OFF_BUFA;
  unsigned* bkt   = (unsigned*)(ws + OFF_BUFA);
  unsigned* cnt   = bkt + BKT_CNT;
  unsigned* total = bkt + BKT_TOTAL;
  unsigned* start = bkt + BKT_START;
  unsigned* curs  = bkt + BKT_CURS;
  unsigned* list  = bkt + BKT_LIST;
  _Float16* Ah = (_Float16*)(ws + OFF_BUFA);
  _Float16* Bh = (_Float16*)(ws + OFF_BUFB);
  _Float16* wt[5] = {(_Float16*)(ws + OFF_WT2), (_Float16*)(ws + OFF_WT3),
                     (_Float16*)(ws + OFF_WT4), (_Float16*)(ws + OFF_WT5),
                     (_Float16*)(ws + OFF_WT6)};

  // zero only the mean accumulator (outputs are fully overwritten each launch)
  hipMemsetAsync(ws + OFF_MEAN, 0, 256 * sizeof(float), stream);

  dim3 blk(256);

  // weight transforms for conv2..conv6
  k_wtrans<<<dim3((32 * 32 * 9 + 255) / 256), blk, 0, stream>>>(wp[1], wt[0], 32, 32);
  k_wtrans<<<dim3((64 * 32 * 9 + 255) / 256), blk, 0, stream>>>(wp[2], wt[1], 64, 32);
  k_wtrans<<<dim3((64 * 64 * 9 + 255) / 256), blk, 0, stream>>>(wp[3], wt[2], 64, 64);
  k_wtrans<<<dim3((96 * 64 * 9 + 255) / 256), blk, 0, stream>>>(wp[4], wt[3], 96, 64);
  k_wtrans<<<dim3((96 * 96 * 9 + 255) / 256), blk, 0, stream>>>(wp[5], wt[4], 96, 96);

  // mean + subtract
  k_mean<<<dim3(32, B), blk, 0, stream>>>(img0, img1, ws + OFF_MEAN, 3 * HW0);
  k_submean<<<dim3((8 * 3 * HW0 + 255) / 256), blk, 0, stream>>>(
      img0, img1, ws + OFF_MEAN, ws + OFF_IMGC, 1.f / (6.f * (float)HW0));

  // intermediate flows (full res)
  k_interflow<<<dim3((B * HW0 + 255) / 256), blk, 0, stream>>>(flow01, sigma01, ws + OFF_FLOW0, 0.5f);
  k_interflow<<<dim3((B * HW0 + 255) / 256), blk, 0, stream>>>(flow10, sigma10, ws + OFF_FLOW1, 0.5f);

  // downsampled flows
  k_downflow<<<dim3((2 * B * HW1 + 255) / 256), blk, 0, stream>>>(ws + OFF_FLOW0, ws + OFF_FL0H, H0, W0, H1, W1, 2);
  k_downflow<<<dim3((2 * B * HW1 + 255) / 256), blk, 0, stream>>>(ws + OFF_FLOW1, ws + OFF_FL1H, H0, W0, H1, W1, 2);
  k_downflow<<<dim3((2 * B * HW2 + 255) / 256), blk, 0, stream>>>(ws + OFF_FLOW0, ws + OFF_FL0Q, H0, W0, H2, W2, 4);
  k_downflow<<<dim3((2 * B * HW2 + 255) / 256), blk, 0, stream>>>(ws + OFF_FLOW1, ws + OFF_FL1Q, H0, W0, H2, W2, 4);

  const float* sigIn[2]  = {sigma01, sigma10};
  const float* flowT[2]  = {ws + OFF_FLOW0, ws + OFF_FLOW1};
  const float* flowTh[2] = {ws + OFF_FL0H, ws + OFF_FL1H};
  const float* flowTq[2] = {ws + OFF_FL0Q, ws + OFF_FL1Q};
  const int NC_F = (W0 + 1) * (H0 + 1), NC_H = (W1 + 1) * (H1 + 1), NC_Q = (W2 + 1) * (H2 + 1);

  for (int im = 0; im < 2; im++) {
    const float* imIn = ws + OFF_IMGC + (size_t)im * 4 * 3 * HW0;
    // conv1: 3->32 full (VALU, -> Ah NHWC f16)
    conv1_nhwc<<<dim3(7 * 64, 4, 4), blk, 0, stream>>>(imIn, wp[0], bp[0], ap[0], Ah);
    // conv2: 32->32 full (MFMA, Ah -> Bh = f01)
    conv_mfma<32, 32, 1><<<dim3(28 * 32, 1, 4), blk, 0, stream>>>(
        Ah, wt[0], bp[1], ap[1], Bh, H0, W0, H0, W0);
    // full-res warp: pack records (A dead) -> exact buckets -> gather
    k_pack_full<<<dim3(HW0 / 256, B), blk, 0, stream>>>(
        ws + OFF_IMGC, Bh, sigIn[im], flowT[im], recs, im);
    hipMemsetAsync(cnt, 0, BKT_ZERO_BYTES, stream);
    k_bucket_count<H0, W0><<<dim3(HW0 / 256, B), blk, 0, stream>>>(flowT[im], cnt);
    k_bucket_alloc<<<dim3((B * NC_F + 255) / 256), blk, 0, stream>>>(
        cnt, start, curs, total, B * NC_F);
    k_bucket_fill<H0, W0><<<dim3(HW0 / 256, B), blk, 0, stream>>>(flowT[im], curs, list);
    k_warp_gather_full<<<dim3(HW0 / 256, B), blk, 0, stream>>>(
        recs, cnt, start, list, out + O_IMG, out + O_F1, out + O_SIG, im);
    // conv3: 32->64 s2 (Bh -> Ah) ; conv4: 64->64 (Ah -> Bh = f02)
    conv_mfma<32, 64, 2><<<dim3(14 * 16, 2, 4), blk, 0, stream>>>(
        Bh, wt[1], bp[2], ap[2], Ah, H0, W0, H1, W1);
    conv_mfma<64, 64, 1><<<dim3(14 * 16, 2, 4), blk, 0, stream>>>(
        Ah, wt[2], bp[3], ap[3], Bh, H1, W1, H1, W1);
    // half-res warp
    k_pack_feat<64, HW1, RS_H><<<dim3(HW1 / 256, B), blk, 0, stream>>>(
        Bh, flowTh[im], recs);
    hipMemsetAsync(cnt, 0, BKT_ZERO_BYTES, stream);
    k_bucket_count<H1, W1><<<dim3(HW1 / 256, B), blk, 0, stream>>>(flowTh[im], cnt);
    k_bucket_alloc<<<dim3((B * NC_H + 255) / 256), blk, 0, stream>>>(
        cnt, start, curs, total, B * NC_H);
    k_bucket_fill<H1, W1><<<dim3(HW1 / 256, B), blk, 0, stream>>>(flowTh[im], curs, list);
    k_warp_gather_feat<64, H1, W1, RS_H><<<dim3(HW1 / 256, B, 2), blk, 0, stream>>>(
        recs, cnt, start, list, out + O_F2, im);
    // conv5: 64->96 s2 (Bh -> Ah) ; conv6: 96->96 (Ah -> Bh = f03)
    conv_mfma<64, 96, 2><<<dim3(7 * 8, 3, 4), blk, 0, stream>>>(
        Bh, wt[3], bp[4], ap[4], Ah, H1, W1, H2, W2);
    conv_mfma<96, 96, 1><<<dim3(7 * 8, 3, 4), blk, 0, stream>>>(
        Ah, wt[4], bp[5], ap[5], Bh, H2, W2, H2, W2);
    // quarter-res warp
    k_pack_feat<96, HW2, RS_Q><<<dim3(HW2 / 256, B), blk, 0, stream>>>(
        Bh, flowTq[im], recs);
    hipMemsetAsync(cnt, 0, BKT_ZERO_BYTES, stream);
    k_bucket_count<H2, W2><<<dim3(HW2 / 256, B), blk, 0, stream>>>(flowTq[im], cnt);
    k_bucket_alloc<<<dim3((B * NC_Q + 255) / 256), blk, 0, stream>>>(
        cnt, start, curs, total, B * NC_Q);
    k_bucket_fill<H2, W2><<<dim3(HW2 / 256, B), blk, 0, stream>>>(flowTq[im], curs, list);
    k_warp_gather_feat<96, H2, W2, RS_Q><<<dim3(HW2 / 256, B, 3), blk, 0, stream>>>(
        recs, cnt, start, list, out + O_F3, im);
  }
}

// Round 6
// 901.921 us; speedup vs baseline: 1.3461x; 1.3461x over previous
//
#include <hip/hip_runtime.h>
#include <hip/hip_fp16.h>

static constexpr int B  = 4;
static constexpr int H0 = 256, W0 = 448, HW0 = H0 * W0;   // full
static constexpr int H1 = 128, W1 = 224, HW1 = H1 * W1;   // half
static constexpr int H2 = 64,  W2 = 112, HW2 = H2 * W2;   // quarter
static constexpr float PI_F = 3.14159265358979323846f;

typedef _Float16 half8_t __attribute__((ext_vector_type(8)));
typedef _Float16 half4_t __attribute__((ext_vector_type(4)));
typedef float floatx4 __attribute__((ext_vector_type(4)));

static constexpr int NC_F = (W0 + 1) * (H0 + 1);   // 115393
static constexpr int NC_H = (W1 + 1) * (H1 + 1);   // 29025
static constexpr int NC_Q = (W2 + 1) * (H2 + 1);   // 7345

// record strides in dwords
static constexpr int RS_F = 20;   // full: u0=(im0,im1) u1=(im2,sig) u2..17=feat pairs u18=fx u19=fy
static constexpr int RS_H = 36;   // 64 ch pairs + fx,fy + pad
static constexpr int RS_Q = 52;   // 96 ch pairs + fx,fy + pad

// ---------------- workspace layout (floats) ----------------
static constexpr size_t OFF_MEAN   = 0;                            // 256
// six per-phase cnt regions + 16 totals, zeroed once together with mean
static constexpr size_t OFF_CNT_F0 = 256;
static constexpr size_t OFF_CNT_F1 = OFF_CNT_F0 + (size_t)B * NC_F;
static constexpr size_t OFF_CNT_H0 = OFF_CNT_F1 + (size_t)B * NC_F;
static constexpr size_t OFF_CNT_H1 = OFF_CNT_H0 + (size_t)B * NC_H;
static constexpr size_t OFF_CNT_Q0 = OFF_CNT_H1 + (size_t)B * NC_H;
static constexpr size_t OFF_CNT_Q1 = OFF_CNT_Q0 + (size_t)B * NC_Q;
static constexpr size_t OFF_TOT    = OFF_CNT_Q1 + (size_t)B * NC_Q;   // 16 slots
static constexpr size_t ZERO_FLOATS = OFF_TOT + 16;                 // memset range
static constexpr size_t OFF_IMGC   = ZERO_FLOATS;                  // 8*3*HW0 planar f32
static constexpr size_t OFF_BUFA   = OFF_IMGC + (size_t)8 * 3 * HW0;   // 8-batch NHWC f16 ping
static constexpr size_t OFF_BUFB   = OFF_BUFA + (size_t)4 * 32 * HW0;  // pong
static constexpr size_t OFF_FLOW0  = OFF_BUFB + (size_t)4 * 32 * HW0;  // B*2*HW0 (dir0)
static constexpr size_t OFF_FLOW1  = OFF_FLOW0 + (size_t)B * 2 * HW0;  // dir1 (contiguous!)
static constexpr size_t OFF_FL0H   = OFF_FLOW1 + (size_t)B * 2 * HW0;  // B*2*HW1 dir0
static constexpr size_t OFF_FL1H   = OFF_FL0H + (size_t)B * 2 * HW1;   // dir1 (contiguous)
static constexpr size_t OFF_FL0Q   = OFF_FL1H + (size_t)B * 2 * HW1;   // B*2*HW2 dir0
static constexpr size_t OFF_FL1Q   = OFF_FL0Q + (size_t)B * 2 * HW2;   // dir1 (contiguous)
static constexpr size_t OFF_WT2 = OFF_FL1Q + (size_t)B * 2 * HW2;  // 9*32*32/2
static constexpr size_t OFF_WT3 = OFF_WT2 + 4608;
static constexpr size_t OFF_WT4 = OFF_WT3 + 9216;
static constexpr size_t OFF_WT5 = OFF_WT4 + 18432;
static constexpr size_t OFF_WT6 = OFF_WT5 + 27648;
static constexpr size_t OFF_START = OFF_WT6 + 41472;               // B*NC_F (max)
static constexpr size_t OFF_CURS  = OFF_START + (size_t)B * NC_F;
static constexpr size_t OFF_LIST  = OFF_CURS + (size_t)B * NC_F;   // B*HW0 (max)
static constexpr size_t OFF_RECS  = OFF_LIST + (size_t)B * HW0;    // B*HW0*RS_F (max)
static constexpr size_t WS_FLOATS = OFF_RECS + (size_t)B * HW0 * RS_F;  // ~46.4M floats

// ---------------- output layout (floats) ----------------
static constexpr size_t O_IMG = 0;
static constexpr size_t O_F1  = O_IMG + (size_t)B * 6 * HW0;
static constexpr size_t O_F2  = O_F1  + (size_t)B * 64 * HW0;
static constexpr size_t O_F3  = O_F2  + (size_t)B * 128 * HW1;
static constexpr size_t O_SIG = O_F3  + (size_t)B * 192 * HW2;

__device__ inline void h2f(unsigned u, float& lo, float& hi) {
  __half2 h = *reinterpret_cast<__half2*>(&u);
  float2 f = __half22float2(h);
  lo = f.x; hi = f.y;
}
__device__ inline unsigned f2h(float lo, float hi) {
  __half2 h = __floats2half2_rn(lo, hi);
  return *reinterpret_cast<unsigned*>(&h);
}

// ---------------- mean over (img0,img1) per batch ----------------
__global__ __launch_bounds__(256) void k_mean(const float* __restrict__ img0,
                                              const float* __restrict__ img1,
                                              float* __restrict__ msum, int perImg) {
  int b = blockIdx.y;
  float s = 0.f;
  int tot = 2 * perImg;
  for (int i = blockIdx.x * blockDim.x + threadIdx.x; i < tot; i += gridDim.x * blockDim.x) {
    s += (i < perImg) ? img0[(size_t)b * perImg + i] : img1[(size_t)b * perImg + (i - perImg)];
  }
#pragma unroll
  for (int o = 32; o > 0; o >>= 1) s += __shfl_down(s, o);
  __shared__ float red[4];
  int lane = threadIdx.x & 63, wid = threadIdx.x >> 6;
  if (lane == 0) red[wid] = s;
  __syncthreads();
  if (threadIdx.x == 0) atomicAdd(&msum[b], red[0] + red[1] + red[2] + red[3]);
}

__global__ __launch_bounds__(256) void k_submean(const float* __restrict__ img0,
                                                 const float* __restrict__ img1,
                                                 const float* __restrict__ msum,
                                                 float* __restrict__ imgc, float invCnt) {
  const int perImg = 3 * HW0;
  int i = blockIdx.x * 256 + threadIdx.x;
  if (i >= 8 * perImg) return;
  int n = i / perImg;
  int r = i - n * perImg;
  int b = n & 3;
  float m = msum[b] * invCnt;
  float v = (n < 4) ? img0[(size_t)b * perImg + r] : img1[(size_t)b * perImg + r];
  imgc[i] = v - m;
}

// ---------------- cal_inter_flow, both dirs (t = 0.5) ----------------
__global__ __launch_bounds__(256) void k_interflow2(
    const float* __restrict__ f01, const float* __restrict__ s01,
    const float* __restrict__ f10, const float* __restrict__ s10,
    float* __restrict__ outBase) {
  int i = blockIdx.x * 256 + threadIdx.x;
  if (i >= 2 * B * HW0) return;
  int dir = i / (B * HW0);
  int r = i - dir * (B * HW0);
  int b = r / HW0, px = r - b * HW0;
  const float* flo = dir ? f10 : f01;
  const float* sigma = dir ? s10 : s01;
  float* out = outBase + (size_t)dir * B * 2 * HW0;
  const float t = 0.5f;
  float fx = flo[((size_t)(b * 2 + 0)) * HW0 + px];
  float fy = flo[((size_t)(b * 2 + 1)) * HW0 + px];
  float sg = sigma[(size_t)b * HW0 + px];
  float ftx, fty;
  if (fabsf(sg) < 0.01f) {
    ftx = t * fx; fty = t * fy;
  } else {
    float alpha = atan2f(fy, fx);
    float beta  = asinf(sg);
    float d = sqrtf(fx * fx + fy * fy);
    float R = d / (2.f * sg);
    float th0 = alpha + 0.5f * PI_F + beta;
    float th1 = alpha + 0.5f * PI_F - beta;
    float tht = th0 + (th1 - th0) * t;
    ftx = R * (cosf(tht) - cosf(th0));
    fty = R * (sinf(tht) - sinf(th0));
  }
  out[((size_t)(b * 2 + 0)) * HW0 + px] = ftx;
  out[((size_t)(b * 2 + 1)) * HW0 + px] = fty;
}

// ---------------- antialiased bilinear downsample (planes covers both dirs) ----------------
__global__ __launch_bounds__(256) void k_downflow(const float* __restrict__ in,
                                                  float* __restrict__ out,
                                                  int Hin, int Win, int Hout, int Wout,
                                                  int F, int planes) {
  int total = planes * Hout * Wout;
  int i = blockIdx.x * 256 + threadIdx.x;
  if (i >= total) return;
  int ow = i % Wout;
  int t  = i / Wout;
  int oh = t % Hout;
  int bc = t / Hout;
  float cy = (oh + 0.5f) * F - 0.5f;
  float cx = (ow + 0.5f) * F - 0.5f;
  int ylo = (int)floorf(cy) - F + 1;
  int xlo = (int)floorf(cx) - F + 1;
  const float* ip = in + (size_t)bc * Hin * Win;
  float acc = 0.f, wn = 0.f;
  for (int jy = 0; jy < 2 * F; jy++) {
    int y = ylo + jy;
    if ((unsigned)y >= (unsigned)Hin) continue;
    float wy = 1.f - fabsf((float)y - cy) / (float)F;
    for (int jx = 0; jx < 2 * F; jx++) {
      int x = xlo + jx;
      if ((unsigned)x >= (unsigned)Win) continue;
      float wx = 1.f - fabsf((float)x - cx) / (float)F;
      float ww = wy * wx;
      acc += ww * ip[(size_t)y * Win + x];
      wn += ww;
    }
  }
  out[i] = (acc / wn) * (1.f / (float)F);
}

// ---------------- all weight transforms fused: [co][ci][3][3] f32 -> [q][co][ci] f16 ----------------
__global__ __launch_bounds__(256) void k_wtrans_all(
    const float* __restrict__ w2, const float* __restrict__ w3,
    const float* __restrict__ w4, const float* __restrict__ w5,
    const float* __restrict__ w6,
    _Float16* __restrict__ o2, _Float16* __restrict__ o3,
    _Float16* __restrict__ o4, _Float16* __restrict__ o5,
    _Float16* __restrict__ o6) {
  int i = blockIdx.x * 256 + threadIdx.x;
  const float* w; _Float16* o; int COUT, CIN, base;
  if      (i <   9216) { w = w2; o = o2; COUT = 32; CIN = 32; base = 0; }
  else if (i <  27648) { w = w3; o = o3; COUT = 64; CIN = 32; base = 9216; }
  else if (i <  64512) { w = w4; o = o4; COUT = 64; CIN = 64; base = 27648; }
  else if (i < 119808) { w = w5; o = o5; COUT = 96; CIN = 64; base = 64512; }
  else if (i < 202752) { w = w6; o = o6; COUT = 96; CIN = 96; base = 119808; }
  else return;
  int j = i - base;
  int q = j % 9;
  int rest = j / 9;
  int ci = rest % CIN;
  int co = rest / CIN;
  o[((size_t)q * COUT + co) * CIN + ci] = (_Float16)w[j];
}

// ---------------- conv1: 3->32, VALU, planar f32 (8 batches) -> NHWC f16 ----------------
__global__ __launch_bounds__(256) void conv1_nhwc(
    const float* __restrict__ in, const float* __restrict__ wgt,
    const float* __restrict__ bias, const float* __restrict__ alpha,
    _Float16* __restrict__ outp) {
  __shared__ float wsm[8 * 3 * 9];
  int co0 = blockIdx.y * 8;
  int n = blockIdx.z;          // 0..7 (dir*4+b)
  for (int i = threadIdx.x; i < 8 * 3 * 9; i += 256) wsm[i] = wgt[co0 * 27 + i];
  __syncthreads();
  int tx = blockIdx.x % 7, ty = blockIdx.x / 7;
  int ow = tx * 64 + (threadIdx.x & 63);
  int oh = ty * 4 + (threadIdx.x >> 6);
  float acc[8];
#pragma unroll
  for (int k = 0; k < 8; k++) acc[k] = bias[co0 + k];
  const float* ip = in + (size_t)n * 3 * HW0;
  for (int ci = 0; ci < 3; ci++) {
    const float* iq = ip + (size_t)ci * HW0;
    float xv[9];
#pragma unroll
    for (int ky = 0; ky < 3; ky++) {
      int y = oh - 1 + ky;
      bool yv = (unsigned)y < (unsigned)H0;
      const float* row = iq + (size_t)y * W0;
#pragma unroll
      for (int kx = 0; kx < 3; kx++) {
        int x = ow - 1 + kx;
        xv[ky * 3 + kx] = (yv && (unsigned)x < (unsigned)W0) ? row[x] : 0.f;
      }
    }
#pragma unroll
    for (int k = 0; k < 8; k++) {
      const float* wp = &wsm[(k * 3 + ci) * 9];
#pragma unroll
      for (int q = 0; q < 9; q++) acc[k] += xv[q] * wp[q];
    }
  }
  float a = alpha[0];
  half8_t h;
#pragma unroll
  for (int k = 0; k < 8; k++) {
    float v = acc[k];
    v = v > 0.f ? v : a * v;
    h[k] = (_Float16)v;
  }
  *(half8_t*)(outp + ((size_t)(n * H0 + oh) * W0 + ow) * 32 + co0) = h;
}

// ---------------- MFMA conv, row-reuse restructure ----------------
// wave tile: 32 co x (4 rows x 16 cols); block: 4 waves = 32 co x 16 rows x 16 cols.
// grid: x = (Wout/16)*(Hout/16), y = COUT/32, z = 8 batches (XCD-chunk swizzled)
template <int CIN, int COUT, int STRIDE>
__global__ __launch_bounds__(256) void conv_mfma(
    const _Float16* __restrict__ in, const _Float16* __restrict__ wT,
    const float* __restrict__ bias, const float* __restrict__ alpha,
    _Float16* __restrict__ outp, int Hin, int Win, int Hout, int Wout) {
  int gx = gridDim.x, gy = gridDim.y, gz = gridDim.z;
  int T = gx * gy * gz;
  int lb = ((int)blockIdx.z * gy + blockIdx.y) * gx + blockIdx.x;
  lb = (lb & 7) * (T >> 3) + (lb >> 3);      // co fastest, n, tile slowest
  int cob  = lb % gy;
  int n    = (lb / gy) % gz;
  int tile = lb / (gy * gz);
  int lane = threadIdx.x & 63, wave = threadIdx.x >> 6;
  int l15 = lane & 15, lhi = lane >> 4;
  int tiles_x = Wout >> 4;
  int tx = tile % tiles_x, ty = tile / tiles_x;
  int ow0 = tx << 4;
  int oh0 = (ty << 4) + (wave << 2);         // wave owns 4 output rows
  int co0 = cob * 32;
  floatx4 acc[2][4] = {};
  const _Float16* ip = in + (size_t)n * Hin * Win * CIN;
  int x_base = (ow0 + l15) * STRIDE;
  int ybase = oh0 * STRIDE - 1;
  constexpr int NY = 3 * STRIDE + 3;         // 6 (s1) or 9 (s2)
  const _Float16* wA = wT + (size_t)(co0 + l15) * CIN;
  const _Float16* wB = wT + (size_t)(co0 + 16 + l15) * CIN;
  for (int kc = 0; kc < CIN / 32; kc++) {
    int ci = kc * 32 + lhi * 8;
#pragma unroll
    for (int dxi = 0; dxi < 3; dxi++) {
      int x = x_base + dxi - 1;
      bool xv = (unsigned)x < (unsigned)Win;
      int xc = x < 0 ? 0 : (x >= Win ? Win - 1 : x);
      half8_t a0[3], a1[3];
#pragma unroll
      for (int dy = 0; dy < 3; dy++) {
        int q = dy * 3 + dxi;
        a0[dy] = *(const half8_t*)(wA + (size_t)q * COUT * CIN + ci);
        a1[dy] = *(const half8_t*)(wB + (size_t)q * COUT * CIN + ci);
      }
#pragma unroll
      for (int y6 = 0; y6 < NY; y6++) {
        int y = ybase + y6;
        if ((unsigned)y >= (unsigned)Hin) continue;   // wave-uniform; skip == zero-pad
        half8_t bf = *(const half8_t*)(ip + ((size_t)y * Win + xc) * CIN + ci);
        half8_t z = {};
        bf = xv ? bf : z;
#pragma unroll
        for (int dy = 0; dy < 3; dy++) {
          int tnum = y6 - dy;
          if (tnum < 0 || tnum % STRIDE != 0) continue;
          int t = tnum / STRIDE;
          if (t >= 4) continue;
          acc[0][t] = __builtin_amdgcn_mfma_f32_16x16x32_f16(a0[dy], bf, acc[0][t], 0, 0, 0);
          acc[1][t] = __builtin_amdgcn_mfma_f32_16x16x32_f16(a1[dy], bf, acc[1][t], 0, 0, 0);
        }
      }
    }
  }
  float aP = alpha[0];
#pragma unroll
  for (int h = 0; h < 2; h++) {
    float bia[4];
#pragma unroll
    for (int r = 0; r < 4; r++) bia[r] = bias[co0 + h * 16 + lhi * 4 + r];
#pragma unroll
    for (int t = 0; t < 4; t++) {
      half4_t hh;
#pragma unroll
      for (int r = 0; r < 4; r++) {
        float v = acc[h][t][r] + bia[r];
        v = v > 0.f ? v : aP * v;
        hh[r] = (_Float16)v;
      }
      *(half4_t*)(outp + (((size_t)n * Hout + oh0 + t) * Wout + ow0 + l15) * COUT +
                  co0 + h * 16 + lhi * 4) = hh;
    }
  }
}

// ---------------- pack warp records (+ fused bucket count) ----------------
__global__ __launch_bounds__(256) void k_pack_full(
    const float* __restrict__ imgc, const _Float16* __restrict__ featN,
    const float* __restrict__ sig, const float* __restrict__ flow,
    float* __restrict__ recs, unsigned* __restrict__ cnt, int dir) {
  constexpr int NCX = W0 + 1;
  int px = blockIdx.x * 256 + threadIdx.x;
  int b = blockIdx.y;
  if (px >= HW0) return;
  const float* imp = imgc + ((size_t)((dir * 4 + b) * 3)) * HW0;
  float im0 = imp[px], im1 = imp[(size_t)HW0 + px], im2 = imp[(size_t)2 * HW0 + px];
  float sg = sig[(size_t)b * HW0 + px];
  float fx = flow[((size_t)(b * 2 + 0)) * HW0 + px];
  float fy = flow[((size_t)(b * 2 + 1)) * HW0 + px];
  union { floatx4 f4[RS_F / 4]; unsigned u[RS_F]; } r;
  r.u[0] = f2h(im0, im1);
  r.u[1] = f2h(im2, sg);
  const floatx4* fp = (const floatx4*)(featN + ((size_t)((dir * 4 + b)) * HW0 + px) * 32);
  union { floatx4 f; unsigned u[4]; } t;
#pragma unroll
  for (int j = 0; j < 4; j++) {
    t.f = fp[j];
    r.u[2 + 4 * j + 0] = t.u[0]; r.u[2 + 4 * j + 1] = t.u[1];
    r.u[2 + 4 * j + 2] = t.u[2]; r.u[2 + 4 * j + 3] = t.u[3];
  }
  r.u[18] = __float_as_uint(fx);
  r.u[19] = __float_as_uint(fy);
  floatx4* o = (floatx4*)(recs + (size_t)(b * HW0 + px) * RS_F);
#pragma unroll
  for (int j = 0; j < RS_F / 4; j++) o[j] = r.f4[j];
  // fused bucket count
  int sw = px % W0, sh = px / W0;
  float tx = (float)sw + fx, ty = (float)sh + fy;
  int x0 = (int)floorf(tx), y0 = (int)floorf(ty);
  if (x0 >= -1 && x0 <= W0 - 1 && y0 >= -1 && y0 <= H0 - 1)
    atomicAdd(&cnt[b * NC_F + (y0 + 1) * NCX + (x0 + 1)], 1u);
}

template <int C, int Hd, int Wd, int RS>
__global__ __launch_bounds__(256) void k_pack_feat(
    const _Float16* __restrict__ featN, const float* __restrict__ flow,
    float* __restrict__ recs, unsigned* __restrict__ cnt, int dir) {
  constexpr int HWd = Hd * Wd;
  constexpr int NCX = Wd + 1;
  constexpr int NC  = (Wd + 1) * (Hd + 1);
  int px = blockIdx.x * 256 + threadIdx.x;
  int b = blockIdx.y;
  if (px >= HWd) return;
  float fx = flow[((size_t)(b * 2 + 0)) * HWd + px];
  float fy = flow[((size_t)(b * 2 + 1)) * HWd + px];
  union { floatx4 f4[RS / 4]; unsigned u[RS]; } r;
  const floatx4* fp = (const floatx4*)(featN + ((size_t)((dir * 4 + b)) * HWd + px) * C);
#pragma unroll
  for (int j = 0; j < C / 8; j++) r.f4[j] = fp[j];
  r.u[C / 2]     = __float_as_uint(fx);
  r.u[C / 2 + 1] = __float_as_uint(fy);
#pragma unroll
  for (int j = C / 2 + 2; j < RS; j++) r.u[j] = 0;
  floatx4* o = (floatx4*)(recs + (size_t)(b * HWd + px) * RS);
#pragma unroll
  for (int j = 0; j < RS / 4; j++) o[j] = r.f4[j];
  int sw = px % Wd, sh = px / Wd;
  float tx = (float)sw + fx, ty = (float)sh + fy;
  int x0 = (int)floorf(tx), y0 = (int)floorf(ty);
  if (x0 >= -1 && x0 <= Wd - 1 && y0 >= -1 && y0 <= Hd - 1)
    atomicAdd(&cnt[b * NC + (y0 + 1) * NCX + (x0 + 1)], 1u);
}

// ---------------- exact buckets: alloc (scan) -> fill ----------------
__global__ __launch_bounds__(256) void k_bucket_alloc(
    const unsigned* __restrict__ cnt, unsigned* __restrict__ start,
    unsigned* __restrict__ curs, unsigned* __restrict__ total, int tot) {
  int i = blockIdx.x * 256 + threadIdx.x;
  unsigned c = (i < tot) ? cnt[i] : 0u;
  unsigned pre = c;
  int lane = threadIdx.x & 63;
#pragma unroll
  for (int o = 1; o < 64; o <<= 1) {
    unsigned v = __shfl_up(pre, o);
    if (lane >= o) pre += v;
  }
  unsigned wsum = __shfl(pre, 63);
  unsigned base = 0;
  if (lane == 0) base = atomicAdd(total, wsum);
  base = __shfl(base, 0);
  unsigned st = base + pre - c;
  if (i < tot) { start[i] = st; curs[i] = st; }
}

template <int Hd, int Wd>
__global__ __launch_bounds__(256) void k_bucket_fill(
    const float* __restrict__ flow, unsigned* __restrict__ curs,
    unsigned* __restrict__ list) {
  constexpr int HWd = Hd * Wd;
  constexpr int NCX = Wd + 1;
  constexpr int NC  = (Wd + 1) * (Hd + 1);
  int px = blockIdx.x * 256 + threadIdx.x;
  int b = blockIdx.y;
  if (px >= HWd) return;
  float fx = flow[((size_t)(b * 2 + 0)) * HWd + px];
  float fy = flow[((size_t)(b * 2 + 1)) * HWd + px];
  int sw = px % Wd, sh = px / Wd;
  float tx = (float)sw + fx, ty = (float)sh + fy;
  int x0 = (int)floorf(tx), y0 = (int)floorf(ty);
  if (x0 < -1 || x0 > Wd - 1 || y0 < -1 || y0 > Hd - 1) return;
  unsigned slot = atomicAdd(&curs[b * NC + (y0 + 1) * NCX + (x0 + 1)], 1u);
  list[slot] = (unsigned)px;
}

// ---------------- full-res gather (normalization fused) ----------------
__global__ __launch_bounds__(256) void k_warp_gather_full(
    const float* __restrict__ recs,
    const unsigned* __restrict__ cnt, const unsigned* __restrict__ start,
    const unsigned* __restrict__ list,
    float* __restrict__ outImg, float* __restrict__ outFeat, float* __restrict__ outSig,
    int dir) {
  constexpr int NCX = W0 + 1;
  int T = gridDim.x * gridDim.y;
  int lb = (int)blockIdx.y * gridDim.x + blockIdx.x;
  lb = (lb & 7) * (T >> 3) + (lb >> 3);          // XCD chunking
  int b = lb / gridDim.x;
  int q = (lb % gridDim.x) * 256 + (int)threadIdx.x;
  if (q >= HW0) return;
  int qx = q % W0, qy = q / W0;
  float acc[36];
#pragma unroll
  for (int c = 0; c < 36; c++) acc[c] = 0.f;
  float dsum = 0.f;
  for (int ky = 0; ky < 2; ky++) {
    int cy = qy - 1 + ky;
    for (int kx = 0; kx < 2; kx++) {
      int cx = qx - 1 + kx;
      int cidx = b * NC_F + (cy + 1) * NCX + (cx + 1);
      unsigned cn = cnt[cidx];
      unsigned s0 = start[cidx];
      for (unsigned s = s0; s < s0 + cn; s++) {
        int px = (int)list[s];
        const floatx4* r4 = (const floatx4*)(recs + (size_t)(b * HW0 + px) * RS_F);
        floatx4 a0 = r4[0], a1 = r4[1], a2 = r4[2], a3 = r4[3], a4 = r4[4];
        union { floatx4 f; unsigned u[4]; } t;
        float ch[36]; float fx, fy;
        t.f = a0; h2f(t.u[0], ch[0], ch[1]);   h2f(t.u[1], ch[2], ch[35]);
                  h2f(t.u[2], ch[3], ch[4]);   h2f(t.u[3], ch[5], ch[6]);
        t.f = a1; h2f(t.u[0], ch[7], ch[8]);   h2f(t.u[1], ch[9], ch[10]);
                  h2f(t.u[2], ch[11], ch[12]); h2f(t.u[3], ch[13], ch[14]);
        t.f = a2; h2f(t.u[0], ch[15], ch[16]); h2f(t.u[1], ch[17], ch[18]);
                  h2f(t.u[2], ch[19], ch[20]); h2f(t.u[3], ch[21], ch[22]);
        t.f = a3; h2f(t.u[0], ch[23], ch[24]); h2f(t.u[1], ch[25], ch[26]);
                  h2f(t.u[2], ch[27], ch[28]); h2f(t.u[3], ch[29], ch[30]);
        t.f = a4; h2f(t.u[0], ch[31], ch[32]); h2f(t.u[1], ch[33], ch[34]);
        fx = __uint_as_float(t.u[2]); fy = __uint_as_float(t.u[3]);
        int sw = px % W0, sh = px / W0;
        float tx = (float)sw + fx, ty = (float)sh + fy;
        float dxf = tx - floorf(tx), dyf = ty - floorf(ty);
        float wx = kx ? (1.f - dxf) : dxf;
        float wy = ky ? (1.f - dyf) : dyf;
        float w = wx * wy;
        dsum += w;
#pragma unroll
        for (int c = 0; c < 36; c++) acc[c] += w * ch[c];
      }
    }
  }
  float inv = 1.f / fmaxf(dsum, 1e-7f);
#pragma unroll
  for (int c = 0; c < 3; c++)
    outImg[((size_t)(b * 6 + dir * 3 + c)) * HW0 + q] = acc[c] * inv;
#pragma unroll
  for (int c = 0; c < 32; c++)
    outFeat[((size_t)(b * 64 + dir * 32 + c)) * HW0 + q] = acc[3 + c] * inv;
  outSig[((size_t)(b * 2 + dir)) * HW0 + q] = acc[35] * inv;
}

// ---------------- reduced-res gather: 32-channel chunk per z (normalization fused) ----------------
template <int C, int Hd, int Wd, int RS>
__global__ __launch_bounds__(256) void k_warp_gather_feat(
    const float* __restrict__ recs,
    const unsigned* __restrict__ cnt, const unsigned* __restrict__ start,
    const unsigned* __restrict__ list,
    float* __restrict__ outF, int dir) {
  constexpr int HWd = Hd * Wd;
  constexpr int NCX = Wd + 1;
  constexpr int NC  = (Wd + 1) * (Hd + 1);
  int Z = gridDim.z;
  int T = gridDim.x * gridDim.y * Z;
  int lb = ((int)blockIdx.z * gridDim.y + blockIdx.y) * gridDim.x + blockIdx.x;
  lb = (lb & 7) * (T >> 3) + (lb >> 3);          // XCD chunking, z fastest
  int z = lb % Z;
  int rest = lb / Z;
  int b = rest / gridDim.x;
  int q = (rest % gridDim.x) * 256 + (int)threadIdx.x;
  int c0 = z * 32;
  if (q >= HWd) return;
  int qx = q % Wd, qy = q / Wd;
  float acc[32];
#pragma unroll
  for (int c = 0; c < 32; c++) acc[c] = 0.f;
  float dsum = 0.f;
  for (int ky = 0; ky < 2; ky++) {
    int cy = qy - 1 + ky;
    for (int kx = 0; kx < 2; kx++) {
      int cx = qx - 1 + kx;
      int cidx = b * NC + (cy + 1) * NCX + (cx + 1);
      unsigned cn = cnt[cidx];
      unsigned s0 = start[cidx];
      for (unsigned s = s0; s < s0 + cn; s++) {
        int px = (int)list[s];
        const unsigned* rp = (const unsigned*)(recs + (size_t)(b * HWd + px) * RS);
        const floatx4* r4 = (const floatx4*)rp;
        floatx4 a0 = r4[4 * z + 0], a1 = r4[4 * z + 1], a2 = r4[4 * z + 2], a3 = r4[4 * z + 3];
        float2 hd = *(const float2*)(rp + C / 2);
        union { floatx4 f; unsigned u[4]; } t;
        float ch[32];
        t.f = a0; h2f(t.u[0], ch[0], ch[1]);  h2f(t.u[1], ch[2], ch[3]);
                  h2f(t.u[2], ch[4], ch[5]);  h2f(t.u[3], ch[6], ch[7]);
        t.f = a1; h2f(t.u[0], ch[8], ch[9]);  h2f(t.u[1], ch[10], ch[11]);
                  h2f(t.u[2], ch[12], ch[13]);h2f(t.u[3], ch[14], ch[15]);
        t.f = a2; h2f(t.u[0], ch[16], ch[17]);h2f(t.u[1], ch[18], ch[19]);
                  h2f(t.u[2], ch[20], ch[21]);h2f(t.u[3], ch[22], ch[23]);
        t.f = a3; h2f(t.u[0], ch[24], ch[25]);h2f(t.u[1], ch[26], ch[27]);
                  h2f(t.u[2], ch[28], ch[29]);h2f(t.u[3], ch[30], ch[31]);
        int sw = px % Wd, sh = px / Wd;
        float tx = (float)sw + hd.x, ty = (float)sh + hd.y;
        float dxf = tx - floorf(tx), dyf = ty - floorf(ty);
        float wx = kx ? (1.f - dxf) : dxf;
        float wy = ky ? (1.f - dyf) : dyf;
        float w = wx * wy;
        dsum += w;
#pragma unroll
        for (int c = 0; c < 32; c++) acc[c] += w * ch[c];
      }
    }
  }
  float inv = 1.f / fmaxf(dsum, 1e-7f);
  size_t obase = ((size_t)(b * 2 * C + dir * C + c0)) * HWd + q;
#pragma unroll
  for (int c = 0; c < 32; c++) outF[obase + (size_t)c * HWd] = acc[c] * inv;
}

extern "C" void kernel_launch(void* const* d_in, const int* in_sizes, int n_in,
                              void* d_out, int out_size, void* d_ws, size_t ws_size,
                              hipStream_t stream) {
  (void)in_sizes; (void)n_in; (void)out_size;
  if (ws_size < WS_FLOATS * sizeof(float)) return;  // not enough scratch

  const float* img0    = (const float*)d_in[0];
  const float* img1    = (const float*)d_in[1];
  const float* flow01  = (const float*)d_in[2];
  const float* sigma01 = (const float*)d_in[3];
  const float* flow10  = (const float*)d_in[4];
  const float* sigma10 = (const float*)d_in[5];
  const float* wp[6]; const float* bp[6]; const float* ap[6];
  for (int i = 0; i < 6; i++) {
    wp[i] = (const float*)(d_in[6 + 3 * i]);
    bp[i] = (const float*)(d_in[7 + 3 * i]);
    ap[i] = (const float*)(d_in[8 + 3 * i]);
  }
  float* ws  = (float*)d_ws;
  float* out = (float*)d_out;

  unsigned* cntF[2] = {(unsigned*)(ws + OFF_CNT_F0), (unsigned*)(ws + OFF_CNT_F1)};
  unsigned* cntH[2] = {(unsigned*)(ws + OFF_CNT_H0), (unsigned*)(ws + OFF_CNT_H1)};
  unsigned* cntQ[2] = {(unsigned*)(ws + OFF_CNT_Q0), (unsigned*)(ws + OFF_CNT_Q1)};
  unsigned* totals  = (unsigned*)(ws + OFF_TOT);
  unsigned* start   = (unsigned*)(ws + OFF_START);
  unsigned* curs    = (unsigned*)(ws + OFF_CURS);
  unsigned* list    = (unsigned*)(ws + OFF_LIST);
  float*    recs    = ws + OFF_RECS;
  _Float16* Ah = (_Float16*)(ws + OFF_BUFA);
  _Float16* Bh = (_Float16*)(ws + OFF_BUFB);
  _Float16* wt[5] = {(_Float16*)(ws + OFF_WT2), (_Float16*)(ws + OFF_WT3),
                     (_Float16*)(ws + OFF_WT4), (_Float16*)(ws + OFF_WT5),
                     (_Float16*)(ws + OFF_WT6)};

  // single upfront zero: mean accumulator + all 6 cnt regions + totals (~4.9 MB)
  hipMemsetAsync(ws, 0, ZERO_FLOATS * sizeof(float), stream);

  dim3 blk(256);

  k_wtrans_all<<<dim3((202752 + 255) / 256), blk, 0, stream>>>(
      wp[1], wp[2], wp[3], wp[4], wp[5], wt[0], wt[1], wt[2], wt[3], wt[4]);

  k_mean<<<dim3(32, B), blk, 0, stream>>>(img0, img1, ws + OFF_MEAN, 3 * HW0);
  k_submean<<<dim3((8 * 3 * HW0 + 255) / 256), blk, 0, stream>>>(
      img0, img1, ws + OFF_MEAN, ws + OFF_IMGC, 1.f / (6.f * (float)HW0));

  k_interflow2<<<dim3((2 * B * HW0 + 255) / 256), blk, 0, stream>>>(
      flow01, sigma01, flow10, sigma10, ws + OFF_FLOW0);

  // downsampled flows, both dirs per call (FLOW0/FLOW1 and FL*H/FL*Q contiguous)
  k_downflow<<<dim3((16 * HW1 + 255) / 256), blk, 0, stream>>>(
      ws + OFF_FLOW0, ws + OFF_FL0H, H0, W0, H1, W1, 2, 16);
  k_downflow<<<dim3((16 * HW2 + 255) / 256), blk, 0, stream>>>(
      ws + OFF_FLOW0, ws + OFF_FL0Q, H0, W0, H2, W2, 4, 16);

  const float* sigIn[2]  = {sigma01, sigma10};
  const float* flowT[2]  = {ws + OFF_FLOW0, ws + OFF_FLOW1};
  const float* flowTh[2] = {ws + OFF_FL0H, ws + OFF_FL1H};
  const float* flowTq[2] = {ws + OFF_FL0Q, ws + OFF_FL1Q};

  // conv1: 3->32 full, 8 batches (VALU) -> Ah ; conv2: 32->32 (MFMA) -> Bh = f01
  conv1_nhwc<<<dim3(7 * 64, 4, 8), blk, 0, stream>>>(ws + OFF_IMGC, wp[0], bp[0], ap[0], Ah);
  conv_mfma<32, 32, 1><<<dim3(28 * 16, 1, 8), blk, 0, stream>>>(
      Ah, wt[0], bp[1], ap[1], Bh, H0, W0, H0, W0);

  // full-res warps (both dirs, sequential over shared recs/start/curs/list)
  for (int dir = 0; dir < 2; dir++) {
    k_pack_full<<<dim3(HW0 / 256, B), blk, 0, stream>>>(
        ws + OFF_IMGC, Bh, sigIn[dir], flowT[dir], recs, cntF[dir], dir);
    k_bucket_alloc<<<dim3((B * NC_F + 255) / 256), blk, 0, stream>>>(
        cntF[dir], start, curs, totals + dir, B * NC_F);
    k_bucket_fill<H0, W0><<<dim3(HW0 / 256, B), blk, 0, stream>>>(flowT[dir], curs, list);
    k_warp_gather_full<<<dim3(HW0 / 256, B), blk, 0, stream>>>(
        recs, cntF[dir], start, list, out + O_IMG, out + O_F1, out + O_SIG, dir);
  }

  // conv3: 32->64 s2 -> Ah ; conv4: 64->64 -> Bh = f02
  conv_mfma<32, 64, 2><<<dim3(14 * 8, 2, 8), blk, 0, stream>>>(
      Bh, wt[1], bp[2], ap[2], Ah, H0, W0, H1, W1);
  conv_mfma<64, 64, 1><<<dim3(14 * 8, 2, 8), blk, 0, stream>>>(
      Ah, wt[2], bp[3], ap[3], Bh, H1, W1, H1, W1);

  for (int dir = 0; dir < 2; dir++) {
    k_pack_feat<64, H1, W1, RS_H><<<dim3(HW1 / 256, B), blk, 0, stream>>>(
        Bh, flowTh[dir], recs, cntH[dir], dir);
    k_bucket_alloc<<<dim3((B * NC_H + 255) / 256), blk, 0, stream>>>(
        cntH[dir], start, curs, totals + 2 + dir, B * NC_H);
    k_bucket_fill<H1, W1><<<dim3(HW1 / 256, B), blk, 0, stream>>>(flowTh[dir], curs, list);
    k_warp_gather_feat<64, H1, W1, RS_H><<<dim3(HW1 / 256, B, 2), blk, 0, stream>>>(
        recs, cntH[dir], start, list, out + O_F2, dir);
  }

  // conv5: 64->96 s2 -> Ah ; conv6: 96->96 -> Bh = f03
  conv_mfma<64, 96, 2><<<dim3(7 * 4, 3, 8), blk, 0, stream>>>(
      Bh, wt[3], bp[4], ap[4], Ah, H1, W1, H2, W2);
  conv_mfma<96, 96, 1><<<dim3(7 * 4, 3, 8), blk, 0, stream>>>(
      Ah, wt[4], bp[5], ap[5], Bh, H2, W2, H2, W2);

  for (int dir = 0; dir < 2; dir++) {
    k_pack_feat<96, H2, W2, RS_Q><<<dim3(HW2 / 256, B), blk, 0, stream>>>(
        Bh, flowTq[dir], recs, cntQ[dir], dir);
    k_bucket_alloc<<<dim3((B * NC_Q + 255) / 256), blk, 0, stream>>>(
        cntQ[dir], start, curs, totals + 4 + dir, B * NC_Q);
    k_bucket_fill<H2, W2><<<dim3(HW2 / 256, B), blk, 0, stream>>>(flowTq[dir], curs, list);
    k_warp_gather_feat<96, H2, W2, RS_Q><<<dim3(HW2 / 256, B, 3), blk, 0, stream>>>(
        recs, cntQ[dir], start, list, out + O_F3, dir);
  }
}